// Round 8
// baseline (485.436 us; speedup 1.0000x reference)
//
#include <hip/hip_runtime.h>

#define NN 50000
#define DIM 128
#define NREL 4
#define NEDGE 200000
#define NLAYER 3
#define SNB 196  // ceil(NN/256)

typedef short s16x8 __attribute__((ext_vector_type(8)));
typedef float f32x4 __attribute__((ext_vector_type(4)));

__device__ __forceinline__ float bf2f(unsigned short u) {
    union { float f; unsigned u; } c; c.u = ((unsigned)u) << 16; return c.f;
}
__device__ __forceinline__ unsigned short f2bf(float f) {
    union { float f; unsigned u; } c; c.f = f;
    unsigned u = c.u + 0x7fffu + ((c.u >> 16) & 1u);
    return (unsigned short)(u >> 16);
}
__device__ __forceinline__ float lo_bf(unsigned u) {
    union { float f; unsigned u; } c; c.u = u << 16; return c.f;
}
__device__ __forceinline__ float hi_bf(unsigned u) {
    union { float f; unsigned u; } c; c.u = u & 0xffff0000u; return c.f;
}

// ---------------- diagnostics ----------------
__global__ __launch_bounds__(256) void k_constf(float* __restrict__ out, int n, float v) {
    int i = blockIdx.x * 256 + threadIdx.x;
    if (i < n) out[i] = v;
}

// ---------------- CSR build ----------------
__global__ __launch_bounds__(256) void k_count(const int* __restrict__ dst, int* __restrict__ counts) {
    int r = blockIdx.y;
    int i = blockIdx.x * 256 + threadIdx.x;
    if (i < NEDGE) {
        int d = dst[r * NEDGE + i];
        if ((unsigned)d < NN) atomicAdd(&counts[r * NN + d], 1);
    }
}

__global__ __launch_bounds__(256) void k_s1(const int* __restrict__ counts, int* __restrict__ bsum) {
    int r = blockIdx.y, b = blockIdx.x;
    int i = b * 256 + threadIdx.x;
    int v = (i < NN) ? counts[r * NN + i] : 0;
    #pragma unroll
    for (int m = 1; m < 64; m <<= 1) v += __shfl_xor(v, m);
    __shared__ int ws[4];
    int wid = threadIdx.x >> 6, lane = threadIdx.x & 63;
    if (lane == 0) ws[wid] = v;
    __syncthreads();
    if (threadIdx.x == 0) bsum[r * SNB + b] = ws[0] + ws[1] + ws[2] + ws[3];
}

__global__ __launch_bounds__(256) void k_s2(const int* __restrict__ bsum, int* __restrict__ boff) {
    int r = threadIdx.x >> 6;   // one wave per relation
    int lane = threadIdx.x & 63;
    int carry = 0;
    for (int c0 = 0; c0 < SNB; c0 += 64) {
        int b = c0 + lane;
        int v = (b < SNB) ? bsum[r * SNB + b] : 0;
        int inc = v;
        #pragma unroll
        for (int d = 1; d < 64; d <<= 1) {
            int t = __shfl_up(inc, d);
            if (lane >= d) inc += t;
        }
        if (b < SNB) boff[r * SNB + b] = carry + inc - v;  // exclusive
        carry += __shfl(inc, 63);
    }
}

__global__ __launch_bounds__(256) void k_s3(const int* __restrict__ counts, const int* __restrict__ boff,
                                            int* __restrict__ row_ptr) {
    int r = blockIdx.y, b = blockIdx.x;
    int i = b * 256 + threadIdx.x;
    int v = (i < NN) ? counts[r * NN + i] : 0;
    int lane = threadIdx.x & 63, wid = threadIdx.x >> 6;
    int inc = v;
    #pragma unroll
    for (int d = 1; d < 64; d <<= 1) {
        int t = __shfl_up(inc, d);
        if (lane >= d) inc += t;
    }
    __shared__ int ws[4];
    if (lane == 63) ws[wid] = inc;
    __syncthreads();
    int woff = 0;
    #pragma unroll
    for (int w = 0; w < 4; ++w) woff += (w < wid) ? ws[w] : 0;
    if (i < NN) row_ptr[r * (NN + 1) + i] = boff[r * SNB + b] + woff + inc - v;
    if (b == 0 && threadIdx.x == 0) row_ptr[r * (NN + 1) + NN] = NEDGE;
}

__global__ __launch_bounds__(256) void k_copynext(const int* __restrict__ row_ptr, int* __restrict__ nxt) {
    int r = blockIdx.y;
    int i = blockIdx.x * 256 + threadIdx.x;
    if (i < NN) nxt[r * NN + i] = row_ptr[r * (NN + 1) + i];
}

__global__ __launch_bounds__(256) void k_fill(const int* __restrict__ src, const int* __restrict__ dst,
                                              int* __restrict__ nxt, int* __restrict__ csr,
                                              int* __restrict__ dstn) {
    int r = blockIdx.y;
    int i = blockIdx.x * 256 + threadIdx.x;
    if (i < NEDGE) {
        int d = dst[r * NEDGE + i];
        if ((unsigned)d >= NN) return;
        int pos = atomicAdd(&nxt[r * NN + d], 1);
        if ((unsigned)pos < NEDGE) {
            csr[r * NEDGE + pos] = src[r * NEDGE + i];
            if (dstn) dstn[r * NEDGE + pos] = d;
        }
    }
}

// ---------------- weight prep (all layers) + h->bf16, one launch ----------------
__global__ __launch_bounds__(256) void k_prep(const float* __restrict__ Wsrc,
                                              const float* __restrict__ Wdst,
                                              const float* __restrict__ ar,
                                              const float* __restrict__ x,
                                              unsigned short* __restrict__ wf,
                                              float* __restrict__ wr,
                                              unsigned short* __restrict__ xb) {
    int b = blockIdx.x;
    if (b < NLAYER * 384) {
        int l = b / 384;
        int t = b % 384;
        if (t < 256) {
            int idx = t * 256 + threadIdx.x;  // 0..65535
            int jj = idx & 7, lane = (idx >> 3) & 63, s = (idx >> 9) & 3, tt = (idx >> 11) & 7, r = idx >> 14;
            int k = s * 32 + ((lane >> 4) << 3) + jj;
            int n = tt * 16 + (lane & 15);
            wf[l * 65536 + idx] = f2bf(Wsrc[((size_t)(l * NREL + r) * DIM + k) * DIM + n]);
        } else {
            int gw = (t - 256) * 4 + (threadIdx.x >> 6);  // 0..511 = r*128+k
            int lane = threadIdx.x & 63;
            int r = gw >> 7, k = gw & 127;
            const float* wrow = Wdst + (((size_t)(l * NREL + r) * DIM + k) * DIM);
            const float* arow = ar + (l * NREL + r) * DIM;
            float s = wrow[lane * 2] * arow[lane * 2] + wrow[lane * 2 + 1] * arow[lane * 2 + 1];
            #pragma unroll
            for (int m = 1; m < 64; m <<= 1) s += __shfl_xor(s, m);
            if (lane == 0) wr[l * 512 + r * 128 + k] = s;
        }
    } else {
        int i = ((b - NLAYER * 384) * 256 + threadIdx.x) * 4;  // NN*DIM/4 elems
        f32x4 v = *(const f32x4*)(x + i);
        unsigned short o[4];
        #pragma unroll
        for (int j = 0; j < 4; ++j) o[j] = f2bf(v[j]);
        *(ushort2*)(xb + i) = make_ushort2(o[0], o[1]);
        *(ushort2*)(xb + i + 2) = make_ushort2(o[2], o[3]);
    }
}

// ---------------- GEMM: hs = xb @ bf16(W_src), el = hs . attn_l ----------------
__global__ __launch_bounds__(256) void k_gemm(const unsigned short* __restrict__ xb,
                                              const unsigned short* __restrict__ wf,
                                              const float* __restrict__ al_all,
                                              unsigned short* __restrict__ hs,
                                              float* __restrict__ el, int l, int rwbase) {
    int ry = blockIdx.y;
    int r = rwbase + ry;
    int wave = threadIdx.x >> 6, lane = threadIdx.x & 63;
    int wbase = blockIdx.x * 256 + wave * 64;
    if (wbase >= NN) return;
    int quad = lane >> 4, n16 = lane & 15;

    s16x8 a[4][4];
    #pragma unroll
    for (int mt = 0; mt < 4; ++mt) {
        int row = wbase + mt * 16 + n16;
        if (row > NN - 1) row = NN - 1;
        const unsigned short* xp = xb + (size_t)row * DIM + quad * 8;
        #pragma unroll
        for (int s = 0; s < 4; ++s) a[mt][s] = *(const s16x8*)(xp + s * 32);
    }

    const float* alp = al_all + (l * NREL + r) * DIM;
    float alv[8];
    #pragma unroll
    for (int t = 0; t < 8; ++t) alv[t] = alp[t * 16 + n16];

    float elp[4][4] = {};
    const s16x8* wfp = (const s16x8*)(wf) + (size_t)(l * NREL + r) * 2048;

    #pragma unroll
    for (int t = 0; t < 8; ++t) {
        s16x8 b[4];
        #pragma unroll
        for (int s = 0; s < 4; ++s) b[s] = wfp[(t * 4 + s) * 64 + lane];
        int col = t * 16 + n16;
        #pragma unroll
        for (int mt = 0; mt < 4; ++mt) {
            f32x4 acc = {0.f, 0.f, 0.f, 0.f};
            #pragma unroll
            for (int s = 0; s < 4; ++s)
                acc = __builtin_amdgcn_mfma_f32_16x16x32_bf16(a[mt][s], b[s], acc, 0, 0, 0);
            #pragma unroll
            for (int reg = 0; reg < 4; ++reg) {
                int row = wbase + mt * 16 + quad * 4 + reg;
                elp[mt][reg] += acc[reg] * alv[t];
                if (row < NN)
                    hs[((size_t)ry * NN + row) * DIM + col] = f2bf(acc[reg]);
            }
        }
    }
    #pragma unroll
    for (int mt = 0; mt < 4; ++mt) {
        #pragma unroll
        for (int reg = 0; reg < 4; ++reg) {
            float v = elp[mt][reg];
            v += __shfl_xor(v, 1); v += __shfl_xor(v, 2);
            v += __shfl_xor(v, 4); v += __shfl_xor(v, 8);
            int row = wbase + mt * 16 + quad * 4 + reg;
            if (n16 == 0 && row < NN) el[ry * NN + row] = v;
        }
    }
}

// ---------------- er[r][n] = x[n] . wr[l,r] (node-parallel, all 4 rels) ----------------
__global__ __launch_bounds__(256) void k_er(const float* __restrict__ x,
                                            const float* __restrict__ wr,
                                            float* __restrict__ er, int l) {
    int oct = threadIdx.x >> 3;
    int ol  = threadIdx.x & 7;
    int n = blockIdx.x * 32 + oct;
    if (n >= NN) return;
    int f0 = ol * 16;
    const float* xp = x + (size_t)n * DIM + f0;
    f32x4 xv[4];
    #pragma unroll
    for (int k = 0; k < 4; ++k) xv[k] = *(const f32x4*)(xp + 4 * k);
    #pragma unroll
    for (int r = 0; r < NREL; ++r) {
        const float* wp = wr + l * 512 + r * DIM + f0;
        float s = 0.f;
        #pragma unroll
        for (int k = 0; k < 4; ++k) {
            f32x4 wv = *(const f32x4*)(wp + 4 * k);
            s += xv[k][0] * wv[0] + xv[k][1] * wv[1] + xv[k][2] * wv[2] + xv[k][3] * wv[3];
        }
        s += __shfl_xor(s, 1); s += __shfl_xor(s, 2); s += __shfl_xor(s, 4);
        if (ol == 0) er[r * NN + n] = s;
    }
}

// ---------------- pw[pos] = exp(leaky(el[src]+er[dst])) (edge-parallel, streamed) ----------------
__global__ __launch_bounds__(256) void k_edgew(const int* __restrict__ csr,
                                               const int* __restrict__ dstn,
                                               const float* __restrict__ el,
                                               const float* __restrict__ er,
                                               float* __restrict__ pw) {
    int r = blockIdx.y;
    int i = blockIdx.x * 256 + threadIdx.x;
    if (i < NEDGE) {
        int s = csr[r * NEDGE + i];
        int d = dstn[r * NEDGE + i];
        if ((unsigned)s >= NN) s = 0;
        if ((unsigned)d >= NN) d = 0;
        float ev = el[r * NN + s] + er[r * NN + d];
        ev = ev >= 0.f ? ev : 0.2f * ev;
        ev = fminf(fmaxf(ev, -60.f), 60.f);
        pw[r * NEDGE + i] = __expf(ev);
    }
}

// ---------------- Path A: 8 nodes x 4 parallel rel-octets per block + LDS combine ----------------
__global__ __launch_bounds__(256) void k_agg2(const unsigned short* __restrict__ hs,
                                              const float* __restrict__ pw,
                                              const int* __restrict__ row_ptr,
                                              const int* __restrict__ csr,
                                              const float* __restrict__ gat_bias,
                                              const float* __restrict__ ntype_bias,
                                              const float* __restrict__ lng,
                                              const float* __restrict__ lnb,
                                              float* __restrict__ xout,
                                              unsigned short* __restrict__ xbout,
                                              int l, int last) {
    __shared__ float sc[NREL][8][DIM];
    int o  = threadIdx.x >> 3;     // 0..31
    int ol = threadIdx.x & 7;
    int nd = o >> 2;               // 0..7
    int r  = o & 3;                // 0..3
    int n = blockIdx.x * 8 + nd;   // NN = 6250*8 exactly
    int f0 = ol * 16;

    int start = row_ptr[r * (NN + 1) + n];
    int end   = row_ptr[r * (NN + 1) + n + 1];
    if (start < 0) start = 0;
    if (end > NEDGE) end = NEDGE;
    int deg = end - start;

    f32x4 av[4] = {{0,0,0,0},{0,0,0,0},{0,0,0,0},{0,0,0,0}};
    float denom = 0.f;
    if (deg > 0) {
        const int* cp = csr + r * NEDGE;
        const float* pp = pw + r * NEDGE;
        const unsigned short* hb0 = hs + (size_t)r * NN * DIM + f0;

        int s0 = cp[start]; if ((unsigned)s0 >= NN) s0 = 0;
        float p0 = pp[start];
        int i1 = (start + 1 < end) ? start + 1 : start;
        int s1 = cp[i1]; if ((unsigned)s1 >= NN) s1 = 0;
        float p1 = pp[i1];
        const uint4* hp = (const uint4*)(hb0 + (size_t)s0 * DIM);
        uint4 ha = hp[0], hb = hp[1];

        for (int e = 0; e < deg; ++e) {
            int i2 = start + e + 2; i2 = (i2 < end) ? i2 : start;
            int s2 = cp[i2]; if ((unsigned)s2 >= NN) s2 = 0;
            float p2 = pp[i2];
            const uint4* hp1 = (const uint4*)(hb0 + (size_t)s1 * DIM);
            uint4 hna = hp1[0], hnb = hp1[1];
            denom += p0;
            av[0][0] += p0 * lo_bf(ha.x); av[0][1] += p0 * hi_bf(ha.x);
            av[0][2] += p0 * lo_bf(ha.y); av[0][3] += p0 * hi_bf(ha.y);
            av[1][0] += p0 * lo_bf(ha.z); av[1][1] += p0 * hi_bf(ha.z);
            av[1][2] += p0 * lo_bf(ha.w); av[1][3] += p0 * hi_bf(ha.w);
            av[2][0] += p0 * lo_bf(hb.x); av[2][1] += p0 * hi_bf(hb.x);
            av[2][2] += p0 * lo_bf(hb.y); av[2][3] += p0 * hi_bf(hb.y);
            av[3][0] += p0 * lo_bf(hb.z); av[3][1] += p0 * hi_bf(hb.z);
            av[3][2] += p0 * lo_bf(hb.w); av[3][3] += p0 * hi_bf(hb.w);
            s1 = s2; p0 = p1; p1 = p2; ha = hna; hb = hnb;
        }
    }
    float inv = (deg > 0) ? (1.0f / denom) : 0.f;
    float* scp = &sc[r][nd][f0];
    #pragma unroll
    for (int k = 0; k < 4; ++k) {
        f32x4 v;
        v[0] = av[k][0] * inv; v[1] = av[k][1] * inv;
        v[2] = av[k][2] * inv; v[3] = av[k][3] * inv;
        *(f32x4*)(scp + 4 * k) = v;
    }
    __syncthreads();

    if (threadIdx.x < 64) {
        int nd2 = threadIdx.x >> 3;   // 0..7
        int ol2 = threadIdx.x & 7;
        int n2 = blockIdx.x * 8 + nd2;
        int g0 = ol2 * 16;
        f32x4 tv[4];
        #pragma unroll
        for (int k = 0; k < 4; ++k) tv[k] = *(const f32x4*)(ntype_bias + l * DIM + g0 + 4 * k);
        #pragma unroll
        for (int q = 0; q < NREL; ++q) {
            const float* sp = &sc[q][nd2][g0];
            #pragma unroll
            for (int k = 0; k < 4; ++k) {
                f32x4 gv = *(const f32x4*)(gat_bias + (l * NREL + q) * DIM + g0 + 4 * k);
                f32x4 sv = *(const f32x4*)(sp + 4 * k);
                tv[k][0] += gv[0] + sv[0]; tv[k][1] += gv[1] + sv[1];
                tv[k][2] += gv[2] + sv[2]; tv[k][3] += gv[3] + sv[3];
            }
        }
        if (!last) {
            #pragma unroll
            for (int k = 0; k < 4; ++k) {
                tv[k][0] = fmaxf(tv[k][0], 0.f); tv[k][1] = fmaxf(tv[k][1], 0.f);
                tv[k][2] = fmaxf(tv[k][2], 0.f); tv[k][3] = fmaxf(tv[k][3], 0.f);
            }
        }
        float s1s = 0.f;
        #pragma unroll
        for (int k = 0; k < 4; ++k) s1s += tv[k][0] + tv[k][1] + tv[k][2] + tv[k][3];
        s1s += __shfl_xor(s1s, 1); s1s += __shfl_xor(s1s, 2); s1s += __shfl_xor(s1s, 4);
        float mean = s1s * (1.0f / 128.0f);
        float s2s = 0.f;
        #pragma unroll
        for (int k = 0; k < 4; ++k) {
            tv[k][0] -= mean; tv[k][1] -= mean; tv[k][2] -= mean; tv[k][3] -= mean;
            s2s += tv[k][0]*tv[k][0] + tv[k][1]*tv[k][1] + tv[k][2]*tv[k][2] + tv[k][3]*tv[k][3];
        }
        s2s += __shfl_xor(s2s, 1); s2s += __shfl_xor(s2s, 2); s2s += __shfl_xor(s2s, 4);
        float rs = rsqrtf(s2s * (1.0f / 128.0f) + 1e-5f);

        float* op = xout + (size_t)n2 * DIM + g0;
        unsigned pk[8];
        #pragma unroll
        for (int k = 0; k < 4; ++k) {
            f32x4 gv = *(const f32x4*)(lng + l * DIM + g0 + 4 * k);
            f32x4 bv = *(const f32x4*)(lnb + l * DIM + g0 + 4 * k);
            f32x4 y;
            y[0] = tv[k][0] * rs * gv[0] + bv[0];
            y[1] = tv[k][1] * rs * gv[1] + bv[1];
            y[2] = tv[k][2] * rs * gv[2] + bv[2];
            y[3] = tv[k][3] * rs * gv[3] + bv[3];
            *(f32x4*)(op + 4 * k) = y;
            pk[2 * k]     = (unsigned)f2bf(y[0]) | ((unsigned)f2bf(y[1]) << 16);
            pk[2 * k + 1] = (unsigned)f2bf(y[2]) | ((unsigned)f2bf(y[3]) << 16);
        }
        uint4* bp = (uint4*)(xbout + (size_t)n2 * DIM + g0);
        uint4 v0; v0.x = pk[0]; v0.y = pk[1]; v0.z = pk[2]; v0.w = pk[3];
        uint4 v1; v1.x = pk[4]; v1.y = pk[5]; v1.z = pk[6]; v1.w = pk[7];
        bp[0] = v0;
        bp[1] = v1;
    }
}

// ---------------- Path B: per-relation aggregate into f32 acc ----------------
__global__ __launch_bounds__(256) void k_aggacc(const float* __restrict__ xin,
                                                const unsigned short* __restrict__ hs1,
                                                const float* __restrict__ el1,
                                                const float* __restrict__ wr,
                                                const int* __restrict__ row_ptr,
                                                const int* __restrict__ csr,
                                                float* __restrict__ acc,
                                                int l, int r, int first) {
    int n = blockIdx.x * 4 + (threadIdx.x >> 6);
    if (n >= NN) return;
    int lane = threadIdx.x & 63;
    int f0 = lane * 2;

    float2 xv = *(const float2*)(xin + (size_t)n * DIM + f0);
    const float2 wv = *(const float2*)(wr + l * 512 + r * DIM + f0);
    float er = xv.x * wv.x + xv.y * wv.y;
    er += __shfl_xor(er, 1); er += __shfl_xor(er, 2); er += __shfl_xor(er, 4);
    er += __shfl_xor(er, 8); er += __shfl_xor(er, 16); er += __shfl_xor(er, 32);

    int start = row_ptr[r * (NN + 1) + n];
    int end = row_ptr[r * (NN + 1) + n + 1];
    if (start < 0) start = 0;
    if (end > NEDGE) end = NEDGE;
    float a0 = 0.f, a1 = 0.f, denom = 0.f;
    for (int e = start; e < end; ++e) {
        int s = csr[r * NEDGE + e];
        if ((unsigned)s >= NN) s = 0;
        float ev = el1[s] + er;
        ev = ev >= 0.f ? ev : 0.2f * ev;
        ev = fminf(fmaxf(ev, -60.f), 60.f);
        float p = __expf(ev);
        denom += p;
        unsigned hv = *(const unsigned*)(hs1 + (size_t)s * DIM + f0);
        a0 += p * bf2f((unsigned short)(hv & 0xffffu));
        a1 += p * bf2f((unsigned short)(hv >> 16));
    }
    float c0 = 0.f, c1 = 0.f;
    if (end > start) { float inv = 1.0f / denom; c0 = a0 * inv; c1 = a1 * inv; }
    float2* ap = (float2*)(acc + (size_t)n * DIM + f0);
    if (!first) { float2 p = *ap; c0 += p.x; c1 += p.y; }
    float2 st; st.x = c0; st.y = c1;
    *ap = st;
}

__global__ __launch_bounds__(256) void k_ln(const float* __restrict__ acc,
                                            const float* __restrict__ gat_bias,
                                            const float* __restrict__ ntype_bias,
                                            const float* __restrict__ lng,
                                            const float* __restrict__ lnb,
                                            float* __restrict__ xout,
                                            unsigned short* __restrict__ xbout,
                                            int l, int last) {
    int n = blockIdx.x * 4 + (threadIdx.x >> 6);
    if (n >= NN) return;
    int lane = threadIdx.x & 63;
    int f0 = lane * 2;
    const float2* ap = (const float2*)(acc + (size_t)n * DIM + f0);
    float2 av = *ap;
    float t0 = av.x + ntype_bias[l * DIM + f0];
    float t1 = av.y + ntype_bias[l * DIM + f0 + 1];
    #pragma unroll
    for (int r = 0; r < 4; ++r) {
        t0 += gat_bias[(l * NREL + r) * DIM + f0];
        t1 += gat_bias[(l * NREL + r) * DIM + f0 + 1];
    }
    if (!last) { t0 = fmaxf(t0, 0.f); t1 = fmaxf(t1, 0.f); }
    float s1 = t0 + t1;
    s1 += __shfl_xor(s1, 1); s1 += __shfl_xor(s1, 2); s1 += __shfl_xor(s1, 4);
    s1 += __shfl_xor(s1, 8); s1 += __shfl_xor(s1, 16); s1 += __shfl_xor(s1, 32);
    float mean = s1 * (1.0f / 128.0f);
    float d0 = t0 - mean, d1 = t1 - mean;
    float s2 = d0 * d0 + d1 * d1;
    s2 += __shfl_xor(s2, 1); s2 += __shfl_xor(s2, 2); s2 += __shfl_xor(s2, 4);
    s2 += __shfl_xor(s2, 8); s2 += __shfl_xor(s2, 16); s2 += __shfl_xor(s2, 32);
    float rs = rsqrtf(s2 * (1.0f / 128.0f) + 1e-5f);
    float g0 = lng[l * DIM + f0], g1 = lng[l * DIM + f0 + 1];
    float b0 = lnb[l * DIM + f0], b1 = lnb[l * DIM + f0 + 1];
    float y0 = d0 * rs * g0 + b0;
    float y1 = d1 * rs * g1 + b1;
    float2 y; y.x = y0; y.y = y1;
    *(float2*)(xout + (size_t)n * DIM + f0) = y;
    unsigned ob = (unsigned)f2bf(y0) | ((unsigned)f2bf(y1) << 16);
    *(unsigned*)(xbout + (size_t)n * DIM + f0) = ob;
}

extern "C" void kernel_launch(void* const* d_in, const int* in_sizes, int n_in,
                              void* d_out, int out_size, void* d_ws, size_t ws_size,
                              hipStream_t stream) {
    const float* h        = (const float*)d_in[0];
    const int*   edge_src = (const int*)d_in[1];
    const int*   edge_dst = (const int*)d_in[2];
    const float* W_src    = (const float*)d_in[3];
    const float* W_dst    = (const float*)d_in[4];
    const float* attn_l   = (const float*)d_in[5];
    const float* attn_r   = (const float*)d_in[6];
    const float* gat_bias = (const float*)d_in[7];
    const float* ntype_b  = (const float*)d_in[8];
    const float* ln_g     = (const float*)d_in[9];
    const float* ln_b     = (const float*)d_in[10];

    if (n_in < 11) return;
    if (in_sizes[0] != NN * DIM) return;
    if (in_sizes[1] != NREL * NEDGE || in_sizes[2] != NREL * NEDGE) return;
    if (in_sizes[3] != NLAYER * NREL * DIM * DIM || in_sizes[4] != NLAYER * NREL * DIM * DIM) return;
    if (in_sizes[5] != NLAYER * NREL * DIM || in_sizes[6] != NLAYER * NREL * DIM) return;
    if (in_sizes[7] != NLAYER * NREL * DIM || in_sizes[8] != NLAYER * DIM) return;
    if (out_size != NN * DIM) return;

    auto align256 = [](size_t x) { return (x + 255) & ~(size_t)255; };
    size_t szHsA = align256((size_t)NREL * NN * DIM * 2);
    size_t szHs1 = align256((size_t)NN * DIM * 2);
    size_t szAcc = align256((size_t)NN * DIM * 4);
    size_t szElA = align256((size_t)NREL * NN * 4);
    size_t szEl1 = align256((size_t)NN * 4);
    size_t szEr  = align256((size_t)NREL * NN * 4);
    size_t szPw  = align256((size_t)NREL * NEDGE * 4);
    size_t szDn  = align256((size_t)NREL * NEDGE * 4);
    size_t szXbf = align256((size_t)NN * DIM * 2);
    size_t szWr  = align256((size_t)NLAYER * NREL * DIM * 4);
    size_t szWf  = align256((size_t)NLAYER * NREL * DIM * DIM * 2);
    size_t szRp  = align256((size_t)NREL * (NN + 1) * 4);
    size_t szNxt = align256((size_t)NREL * NN * 4);
    size_t szCsr = align256((size_t)NREL * NEDGE * 4);
    size_t szScn = align256((size_t)NREL * SNB * 4) * 2;
    size_t common = szXbf + szWr + szWf + szRp + szNxt + szCsr + szScn;
    size_t needA = szHsA + szElA + szEr + szPw + szDn + common;
    size_t needB = szHs1 + szAcc + szEl1 + common;

    if (ws_size < needB) {
        k_constf<<<(NN * DIM + 255) / 256, 256, 0, stream>>>((float*)d_out, NN * DIM, 100.0f);
        return;
    }
    int pathA = (ws_size >= needA) ? 1 : 0;

    char* base = (char*)d_ws;
    size_t off = 0;
    auto alloc = [&](size_t bytes) -> char* { char* p = base + off; off += align256(bytes); return p; };

    unsigned short* hs   = nullptr;
    float*          acc  = nullptr;
    float*          el   = nullptr;
    float*          er   = nullptr;
    float*          pw   = nullptr;
    int*            dstn = nullptr;
    if (pathA) {
        hs   = (unsigned short*)alloc((size_t)NREL * NN * DIM * 2);
        el   = (float*)alloc((size_t)NREL * NN * 4);
        er   = (float*)alloc((size_t)NREL * NN * 4);
        pw   = (float*)alloc((size_t)NREL * NEDGE * 4);
        dstn = (int*)alloc((size_t)NREL * NEDGE * 4);
    } else {
        hs  = (unsigned short*)alloc((size_t)NN * DIM * 2);
        acc = (float*)alloc((size_t)NN * DIM * 4);
        el  = (float*)alloc((size_t)NN * 4);
    }
    unsigned short* xbf   = (unsigned short*)alloc((size_t)NN * DIM * 2);
    float*          wr    = (float*)alloc((size_t)NLAYER * NREL * DIM * 4);
    unsigned short* wfrag = (unsigned short*)alloc((size_t)NLAYER * NREL * DIM * DIM * 2);
    int*            rowp  = (int*)alloc((size_t)NREL * (NN + 1) * 4);
    int*            nxt   = (int*)alloc((size_t)NREL * NN * 4);
    int*            csr   = (int*)alloc((size_t)NREL * NEDGE * 4);
    int*            bsum  = (int*)alloc((size_t)NREL * SNB * 4);
    int*            boff  = (int*)alloc((size_t)NREL * SNB * 4);

    // ---- CSR build (hierarchical scan) + all-layer weight prep + h->bf16 ----
    (void)hipMemsetAsync(nxt, 0, (size_t)NREL * NN * 4, stream);
    k_count<<<dim3((NEDGE + 255) / 256, NREL), 256, 0, stream>>>(edge_dst, nxt);
    k_s1<<<dim3(SNB, NREL), 256, 0, stream>>>(nxt, bsum);
    k_s2<<<1, 256, 0, stream>>>(bsum, boff);
    k_s3<<<dim3(SNB, NREL), 256, 0, stream>>>(nxt, boff, rowp);
    k_copynext<<<dim3((NN + 255) / 256, NREL), 256, 0, stream>>>(rowp, nxt);
    k_fill<<<dim3((NEDGE + 255) / 256, NREL), 256, 0, stream>>>(edge_src, edge_dst, nxt, csr, dstn);
    k_prep<<<NLAYER * 384 + NN * DIM / 1024, 256, 0, stream>>>(W_src, W_dst, attn_r, h, wfrag, wr, xbf);

    // ---- layers (f32 x in-place in d_out; bf16 x in xbf) ----
    const float* xin = h;
    float* xout = (float*)d_out;
    for (int l = 0; l < NLAYER; ++l) {
        int last = (l == NLAYER - 1) ? 1 : 0;
        if (pathA) {
            k_gemm<<<dim3((NN + 255) / 256, NREL), 256, 0, stream>>>(xbf, wfrag, attn_l, hs, el, l, 0);
            k_er<<<(NN + 31) / 32, 256, 0, stream>>>(xin, wr, er, l);
            k_edgew<<<dim3((NEDGE + 255) / 256, NREL), 256, 0, stream>>>(csr, dstn, el, er, pw);
            k_agg2<<<NN / 8, 256, 0, stream>>>(hs, pw, rowp, csr,
                                               gat_bias, ntype_b, ln_g, ln_b, xout, xbf, l, last);
        } else {
            for (int r = 0; r < NREL; ++r) {
                k_gemm<<<dim3((NN + 255) / 256, 1), 256, 0, stream>>>(xbf, wfrag, attn_l, hs, el, l, r);
                k_aggacc<<<NN / 4, 256, 0, stream>>>(xin, hs, el, wr, rowp, csr, acc, l, r, r == 0 ? 1 : 0);
            }
            k_ln<<<NN / 4, 256, 0, stream>>>(acc, gat_bias, ntype_b, ln_g, ln_b, xout, xbf, l, last);
        }
        xin = xout;
    }
}

// Round 9
// 351.686 us; speedup vs baseline: 1.3803x; 1.3803x over previous
//
#include <hip/hip_runtime.h>

#define NN 50000
#define DIM 128
#define NREL 4
#define NEDGE 200000
#define NLAYER 3
#define SNB 196  // ceil(NN/256)

typedef short s16x8 __attribute__((ext_vector_type(8)));
typedef float f32x4 __attribute__((ext_vector_type(4)));

__device__ __forceinline__ unsigned short f2bf(float f) {
    union { float f; unsigned u; } c; c.f = f;
    unsigned u = c.u + 0x7fffu + ((c.u >> 16) & 1u);
    return (unsigned short)(u >> 16);
}
__device__ __forceinline__ float lo_bf(unsigned u) {
    union { float f; unsigned u; } c; c.u = u << 16; return c.f;
}
__device__ __forceinline__ float hi_bf(unsigned u) {
    union { float f; unsigned u; } c; c.u = u & 0xffff0000u; return c.f;
}

// ---------------- diagnostics ----------------
__global__ __launch_bounds__(256) void k_constf(float* __restrict__ out, int n, float v) {
    int i = blockIdx.x * 256 + threadIdx.x;
    if (i < n) out[i] = v;
}

// ---------------- CSR build ----------------
__global__ __launch_bounds__(256) void k_count(const int* __restrict__ dst, int* __restrict__ counts) {
    int r = blockIdx.y;
    int i = blockIdx.x * 256 + threadIdx.x;
    if (i < NEDGE) {
        int d = dst[r * NEDGE + i];
        if ((unsigned)d < NN) atomicAdd(&counts[r * NN + d], 1);
    }
}

__global__ __launch_bounds__(256) void k_s1(const int* __restrict__ counts, int* __restrict__ bsum) {
    int r = blockIdx.y, b = blockIdx.x;
    int i = b * 256 + threadIdx.x;
    int v = (i < NN) ? counts[r * NN + i] : 0;
    #pragma unroll
    for (int m = 1; m < 64; m <<= 1) v += __shfl_xor(v, m);
    __shared__ int ws[4];
    int wid = threadIdx.x >> 6, lane = threadIdx.x & 63;
    if (lane == 0) ws[wid] = v;
    __syncthreads();
    if (threadIdx.x == 0) bsum[r * SNB + b] = ws[0] + ws[1] + ws[2] + ws[3];
}

__global__ __launch_bounds__(256) void k_s2(const int* __restrict__ bsum, int* __restrict__ boff) {
    int r = threadIdx.x >> 6;
    int lane = threadIdx.x & 63;
    int carry = 0;
    for (int c0 = 0; c0 < SNB; c0 += 64) {
        int b = c0 + lane;
        int v = (b < SNB) ? bsum[r * SNB + b] : 0;
        int inc = v;
        #pragma unroll
        for (int d = 1; d < 64; d <<= 1) {
            int t = __shfl_up(inc, d);
            if (lane >= d) inc += t;
        }
        if (b < SNB) boff[r * SNB + b] = carry + inc - v;
        carry += __shfl(inc, 63);
    }
}

__global__ __launch_bounds__(256) void k_s3(const int* __restrict__ counts, const int* __restrict__ boff,
                                            int* __restrict__ row_ptr) {
    int r = blockIdx.y, b = blockIdx.x;
    int i = b * 256 + threadIdx.x;
    int v = (i < NN) ? counts[r * NN + i] : 0;
    int lane = threadIdx.x & 63, wid = threadIdx.x >> 6;
    int inc = v;
    #pragma unroll
    for (int d = 1; d < 64; d <<= 1) {
        int t = __shfl_up(inc, d);
        if (lane >= d) inc += t;
    }
    __shared__ int ws[4];
    if (lane == 63) ws[wid] = inc;
    __syncthreads();
    int woff = 0;
    #pragma unroll
    for (int w = 0; w < 4; ++w) woff += (w < wid) ? ws[w] : 0;
    if (i < NN) row_ptr[r * (NN + 1) + i] = boff[r * SNB + b] + woff + inc - v;
    if (b == 0 && threadIdx.x == 0) row_ptr[r * (NN + 1) + NN] = NEDGE;
}

__global__ __launch_bounds__(256) void k_copynext(const int* __restrict__ row_ptr, int* __restrict__ nxt) {
    int r = blockIdx.y;
    int i = blockIdx.x * 256 + threadIdx.x;
    if (i < NN) nxt[r * NN + i] = row_ptr[r * (NN + 1) + i];
}

__global__ __launch_bounds__(256) void k_fill(const int* __restrict__ src, const int* __restrict__ dst,
                                              int* __restrict__ nxt, int* __restrict__ csr) {
    int r = blockIdx.y;
    int i = blockIdx.x * 256 + threadIdx.x;
    if (i < NEDGE) {
        int d = dst[r * NEDGE + i];
        if ((unsigned)d >= NN) return;
        int pos = atomicAdd(&nxt[r * NN + d], 1);
        if ((unsigned)pos < NEDGE) csr[r * NEDGE + pos] = src[r * NEDGE + i];
    }
}

// ---------------- prep: wfrag + wl + wr + combined bias + h->bf16 ----------------
// per layer: 256 wfrag blocks + 128 wl blocks + 128 wr blocks = 512
__global__ __launch_bounds__(256) void k_prep(const float* __restrict__ Wsrc,
                                              const float* __restrict__ Wdst,
                                              const float* __restrict__ al,
                                              const float* __restrict__ ar,
                                              const float* __restrict__ ntb,
                                              const float* __restrict__ gb,
                                              const float* __restrict__ x,
                                              unsigned short* __restrict__ wf,
                                              float* __restrict__ wl,
                                              float* __restrict__ wr,
                                              float* __restrict__ biasc,
                                              unsigned short* __restrict__ xb) {
    int b = blockIdx.x;
    const int PL = NLAYER * 512;
    if (b < PL) {
        int l = b / 512;
        int t = b % 512;
        if (t < 256) {
            int idx = t * 256 + threadIdx.x;  // 0..65535
            int jj = idx & 7, lane = (idx >> 3) & 63, s = (idx >> 9) & 3, tt = (idx >> 11) & 7, r = idx >> 14;
            int k = s * 32 + ((lane >> 4) << 3) + jj;
            int n = tt * 16 + (lane & 15);
            wf[l * 65536 + idx] = f2bf(Wsrc[((size_t)(l * NREL + r) * DIM + k) * DIM + n]);
        } else if (t < 384) {
            int gw = (t - 256) * 4 + (threadIdx.x >> 6);  // 0..511 = r*128+k
            int lane = threadIdx.x & 63;
            int r = gw >> 7, k = gw & 127;
            const float* wrow = Wsrc + (((size_t)(l * NREL + r) * DIM + k) * DIM);
            const float* arow = al + (l * NREL + r) * DIM;
            float s = wrow[lane * 2] * arow[lane * 2] + wrow[lane * 2 + 1] * arow[lane * 2 + 1];
            #pragma unroll
            for (int m = 1; m < 64; m <<= 1) s += __shfl_xor(s, m);
            if (lane == 0) wl[l * 512 + gw] = s;
        } else {
            int gw = (t - 384) * 4 + (threadIdx.x >> 6);
            int lane = threadIdx.x & 63;
            int r = gw >> 7, k = gw & 127;
            const float* wrow = Wdst + (((size_t)(l * NREL + r) * DIM + k) * DIM);
            const float* arow = ar + (l * NREL + r) * DIM;
            float s = wrow[lane * 2] * arow[lane * 2] + wrow[lane * 2 + 1] * arow[lane * 2 + 1];
            #pragma unroll
            for (int m = 1; m < 64; m <<= 1) s += __shfl_xor(s, m);
            if (lane == 0) wr[l * 512 + gw] = s;
        }
    } else if (b < PL + 2) {
        int t = (b - PL) * 256 + threadIdx.x;
        if (t < NLAYER * DIM) {
            int l = t >> 7, k = t & 127;
            float s = ntb[t];
            #pragma unroll
            for (int r = 0; r < NREL; ++r) s += gb[(l * NREL + r) * DIM + k];
            biasc[t] = s;
        }
    } else {
        int i = ((b - PL - 2) * 256 + threadIdx.x) * 4;
        f32x4 v = *(const f32x4*)(x + i);
        unsigned short o[4];
        #pragma unroll
        for (int j = 0; j < 4; ++j) o[j] = f2bf(v[j]);
        *(ushort2*)(xb + i) = make_ushort2(o[0], o[1]);
        *(ushort2*)(xb + i + 2) = make_ushort2(o[2], o[3]);
    }
}

// ---------------- el/er for layer 0 from f32 h ----------------
__global__ __launch_bounds__(256) void k_er0(const float* __restrict__ x,
                                             const float* __restrict__ wl,
                                             const float* __restrict__ wr,
                                             float* __restrict__ el,
                                             float* __restrict__ er) {
    int oct = threadIdx.x >> 3, ol = threadIdx.x & 7;
    int n = blockIdx.x * 32 + oct;
    if (n >= NN) return;
    int f0 = ol * 16;
    const float* xp = x + (size_t)n * DIM + f0;
    f32x4 xv[4];
    #pragma unroll
    for (int k = 0; k < 4; ++k) xv[k] = *(const f32x4*)(xp + 4 * k);
    #pragma unroll
    for (int r = 0; r < NREL; ++r) {
        float sl = 0.f, sr = 0.f;
        #pragma unroll
        for (int k = 0; k < 4; ++k) {
            f32x4 lv = *(const f32x4*)(wl + r * DIM + f0 + 4 * k);
            f32x4 rv = *(const f32x4*)(wr + r * DIM + f0 + 4 * k);
            sl += xv[k][0] * lv[0] + xv[k][1] * lv[1] + xv[k][2] * lv[2] + xv[k][3] * lv[3];
            sr += xv[k][0] * rv[0] + xv[k][1] * rv[1] + xv[k][2] * rv[2] + xv[k][3] * rv[3];
        }
        sl += __shfl_xor(sl, 1); sl += __shfl_xor(sl, 2); sl += __shfl_xor(sl, 4);
        sr += __shfl_xor(sr, 1); sr += __shfl_xor(sr, 2); sr += __shfl_xor(sr, 4);
        if (ol == 0) { el[r * NN + n] = sl; er[r * NN + n] = sr; }
    }
}

// ---------------- fused layer: aggregate x -> LDS A-frags -> MFMA -> LN -> el'/er' ----------------
// 16 nodes per block; 64 node-rel pairs x 4 lanes (32 feats each) for the gather;
// K=512 MFMA (4 rels concatenated); epilogue LN + next-layer el/er.
__global__ __launch_bounds__(256) void k_fused(const unsigned short* __restrict__ xb,
                                               const float* __restrict__ el,
                                               const float* __restrict__ er,
                                               const int* __restrict__ row_ptr,
                                               const int* __restrict__ csr,
                                               const unsigned short* __restrict__ wf,
                                               const float* __restrict__ biasc,
                                               const float* __restrict__ lng,
                                               const float* __restrict__ lnb,
                                               const float* __restrict__ wl,
                                               const float* __restrict__ wr,
                                               float* __restrict__ dout,
                                               unsigned short* __restrict__ xb2,
                                               float* __restrict__ el2,
                                               float* __restrict__ er2,
                                               int l, int last) {
    __shared__ s16x8 lds_a[16 * 64];   // 16KB A-frags; reused as float C[16][128]
    int tid = threadIdx.x;

    // ---- phase 1: attention-weighted aggregation of x (bf16) ----
    {
        int pair = tid >> 2;        // 0..63
        int ol   = tid & 3;         // lane in pair
        int nd   = pair >> 2;       // 0..15
        int r    = pair & 3;
        int n    = blockIdx.x * 16 + nd;
        int f0   = ol * 32;

        int start = row_ptr[r * (NN + 1) + n];
        int end   = row_ptr[r * (NN + 1) + n + 1];
        if (start < 0) start = 0;
        if (end > NEDGE) end = NEDGE;
        int deg = end - start;

        float ern = er[r * NN + n];
        const int* cp = csr + r * NEDGE;
        const float* elp = el + r * NN;

        f32x4 av[8] = {{0,0,0,0},{0,0,0,0},{0,0,0,0},{0,0,0,0},
                       {0,0,0,0},{0,0,0,0},{0,0,0,0},{0,0,0,0}};
        float denom = 0.f;
        if (deg > 0) {
            int s0 = cp[start]; if ((unsigned)s0 >= NN) s0 = 0;
            float e0 = elp[s0];
            const uint4* hp = (const uint4*)(xb + (size_t)s0 * DIM + f0);
            uint4 xa = hp[0], xbv = hp[1], xc = hp[2], xd = hp[3];
            for (int e = 0; e < deg; ++e) {
                int i1 = start + e + 1; i1 = (i1 < end) ? i1 : start;
                int s1 = cp[i1]; if ((unsigned)s1 >= NN) s1 = 0;
                float e1 = elp[s1];
                const uint4* hp1 = (const uint4*)(xb + (size_t)s1 * DIM + f0);
                uint4 ya = hp1[0], yb = hp1[1], yc = hp1[2], yd = hp1[3];

                float ev = e0 + ern;
                ev = ev >= 0.f ? ev : 0.2f * ev;
                ev = fminf(fmaxf(ev, -60.f), 60.f);
                float p = __expf(ev);
                denom += p;
                av[0][0] += p * lo_bf(xa.x); av[0][1] += p * hi_bf(xa.x);
                av[0][2] += p * lo_bf(xa.y); av[0][3] += p * hi_bf(xa.y);
                av[1][0] += p * lo_bf(xa.z); av[1][1] += p * hi_bf(xa.z);
                av[1][2] += p * lo_bf(xa.w); av[1][3] += p * hi_bf(xa.w);
                av[2][0] += p * lo_bf(xbv.x); av[2][1] += p * hi_bf(xbv.x);
                av[2][2] += p * lo_bf(xbv.y); av[2][3] += p * hi_bf(xbv.y);
                av[3][0] += p * lo_bf(xbv.z); av[3][1] += p * hi_bf(xbv.z);
                av[3][2] += p * lo_bf(xbv.w); av[3][3] += p * hi_bf(xbv.w);
                av[4][0] += p * lo_bf(xc.x); av[4][1] += p * hi_bf(xc.x);
                av[4][2] += p * lo_bf(xc.y); av[4][3] += p * hi_bf(xc.y);
                av[5][0] += p * lo_bf(xc.z); av[5][1] += p * hi_bf(xc.z);
                av[5][2] += p * lo_bf(xc.w); av[5][3] += p * hi_bf(xc.w);
                av[6][0] += p * lo_bf(xd.x); av[6][1] += p * hi_bf(xd.x);
                av[6][2] += p * lo_bf(xd.y); av[6][3] += p * hi_bf(xd.y);
                av[7][0] += p * lo_bf(xd.z); av[7][1] += p * hi_bf(xd.z);
                av[7][2] += p * lo_bf(xd.w); av[7][3] += p * hi_bf(xd.w);
                e0 = e1; xa = ya; xbv = yb; xc = yc; xd = yd;
            }
        }
        float inv = (deg > 0) ? (1.0f / denom) : 0.f;
        // pack to bf16 A-frags: lane covers k = r*128 + ol*32 + [0,32)
        #pragma unroll
        for (int q = 0; q < 4; ++q) {
            s16x8 o;
            #pragma unroll
            for (int j = 0; j < 4; ++j) {
                o[j]     = (short)f2bf(av[2 * q][j] * inv);
                o[j + 4] = (short)f2bf(av[2 * q + 1][j] * inv);
            }
            lds_a[(r * 4 + ol) * 64 + q * 16 + nd] = o;
        }
    }
    __syncthreads();

    // ---- phase 2: C[16x128] = A[16x512] @ W[512x128] ----
    int wv = tid >> 6, lane = tid & 63;
    int quad = lane >> 4, n16 = lane & 15;
    f32x4 acc0 = {0.f, 0.f, 0.f, 0.f}, acc1 = {0.f, 0.f, 0.f, 0.f};
    {
        const s16x8* wfp = (const s16x8*)wf + (size_t)l * NREL * 2048;
        int t0c = wv * 2, t1c = wv * 2 + 1;
        #pragma unroll
        for (int sp = 0; sp < 16; ++sp) {
            s16x8 a = lds_a[sp * 64 + lane];
            const s16x8* wb = wfp + (size_t)(sp >> 2) * 2048;
            int sl = sp & 3;
            s16x8 b0 = wb[(t0c * 4 + sl) * 64 + lane];
            s16x8 b1 = wb[(t1c * 4 + sl) * 64 + lane];
            acc0 = __builtin_amdgcn_mfma_f32_16x16x32_bf16(a, b0, acc0, 0, 0, 0);
            acc1 = __builtin_amdgcn_mfma_f32_16x16x32_bf16(a, b1, acc1, 0, 0, 0);
        }
    }
    __syncthreads();
    float* Cl = (float*)lds_a;
    {
        int t0c = wv * 2, t1c = wv * 2 + 1;
        #pragma unroll
        for (int reg = 0; reg < 4; ++reg) {
            int row = quad * 4 + reg;
            Cl[row * DIM + t0c * 16 + n16] = acc0[reg];
            Cl[row * DIM + t1c * 16 + n16] = acc1[reg];
        }
    }
    __syncthreads();

    // ---- phase 3: bias + ReLU + LayerNorm + outputs + next-layer el'/er' ----
    {
        int nd2 = tid >> 4;         // 0..15
        int sub = tid & 15;
        int f   = sub * 8;
        int n2  = blockIdx.x * 16 + nd2;

        float t[8];
        #pragma unroll
        for (int j = 0; j < 8; ++j) t[j] = Cl[nd2 * DIM + f + j] + biasc[l * DIM + f + j];
        if (!last) {
            #pragma unroll
            for (int j = 0; j < 8; ++j) t[j] = fmaxf(t[j], 0.f);
        }
        float s1 = 0.f;
        #pragma unroll
        for (int j = 0; j < 8; ++j) s1 += t[j];
        s1 += __shfl_xor(s1, 1); s1 += __shfl_xor(s1, 2);
        s1 += __shfl_xor(s1, 4); s1 += __shfl_xor(s1, 8);
        float mean = s1 * (1.0f / 128.0f);
        float s2 = 0.f;
        #pragma unroll
        for (int j = 0; j < 8; ++j) { t[j] -= mean; s2 += t[j] * t[j]; }
        s2 += __shfl_xor(s2, 1); s2 += __shfl_xor(s2, 2);
        s2 += __shfl_xor(s2, 4); s2 += __shfl_xor(s2, 8);
        float rs = rsqrtf(s2 * (1.0f / 128.0f) + 1e-5f);

        float y[8];
        #pragma unroll
        for (int j = 0; j < 8; ++j)
            y[j] = t[j] * rs * lng[l * DIM + f + j] + lnb[l * DIM + f + j];

        if (last) {
            float* op = dout + (size_t)n2 * DIM + f;
            f32x4 v0, v1;
            v0[0] = y[0]; v0[1] = y[1]; v0[2] = y[2]; v0[3] = y[3];
            v1[0] = y[4]; v1[1] = y[5]; v1[2] = y[6]; v1[3] = y[7];
            *(f32x4*)op = v0;
            *(f32x4*)(op + 4) = v1;
        } else {
            unsigned pk[4];
            #pragma unroll
            for (int j = 0; j < 4; ++j)
                pk[j] = (unsigned)f2bf(y[2 * j]) | ((unsigned)f2bf(y[2 * j + 1]) << 16);
            uint4 v; v.x = pk[0]; v.y = pk[1]; v.z = pk[2]; v.w = pk[3];
            *(uint4*)(xb2 + (size_t)n2 * DIM + f) = v;

            const float* wlp = wl + (l + 1) * 512;
            const float* wrp = wr + (l + 1) * 512;
            #pragma unroll
            for (int rp = 0; rp < NREL; ++rp) {
                float sl_ = 0.f, sr_ = 0.f;
                #pragma unroll
                for (int j = 0; j < 8; ++j) {
                    sl_ += y[j] * wlp[rp * DIM + f + j];
                    sr_ += y[j] * wrp[rp * DIM + f + j];
                }
                sl_ += __shfl_xor(sl_, 1); sl_ += __shfl_xor(sl_, 2);
                sl_ += __shfl_xor(sl_, 4); sl_ += __shfl_xor(sl_, 8);
                sr_ += __shfl_xor(sr_, 1); sr_ += __shfl_xor(sr_, 2);
                sr_ += __shfl_xor(sr_, 4); sr_ += __shfl_xor(sr_, 8);
                if (sub == 0) {
                    el2[rp * NN + n2] = sl_;
                    er2[rp * NN + n2] = sr_;
                }
            }
        }
    }
}

extern "C" void kernel_launch(void* const* d_in, const int* in_sizes, int n_in,
                              void* d_out, int out_size, void* d_ws, size_t ws_size,
                              hipStream_t stream) {
    const float* h        = (const float*)d_in[0];
    const int*   edge_src = (const int*)d_in[1];
    const int*   edge_dst = (const int*)d_in[2];
    const float* W_src    = (const float*)d_in[3];
    const float* W_dst    = (const float*)d_in[4];
    const float* attn_l   = (const float*)d_in[5];
    const float* attn_r   = (const float*)d_in[6];
    const float* gat_bias = (const float*)d_in[7];
    const float* ntype_b  = (const float*)d_in[8];
    const float* ln_g     = (const float*)d_in[9];
    const float* ln_b     = (const float*)d_in[10];

    if (n_in < 11) return;
    if (in_sizes[0] != NN * DIM) return;
    if (in_sizes[1] != NREL * NEDGE || in_sizes[2] != NREL * NEDGE) return;
    if (in_sizes[3] != NLAYER * NREL * DIM * DIM || in_sizes[4] != NLAYER * NREL * DIM * DIM) return;
    if (in_sizes[5] != NLAYER * NREL * DIM || in_sizes[6] != NLAYER * NREL * DIM) return;
    if (in_sizes[7] != NLAYER * NREL * DIM || in_sizes[8] != NLAYER * DIM) return;
    if (out_size != NN * DIM) return;

    auto align256 = [](size_t x) { return (x + 255) & ~(size_t)255; };
    size_t szElEr = align256((size_t)NREL * NN * 4);            // x4 buffers
    size_t szXbf  = align256((size_t)NN * DIM * 2);             // x2 buffers
    size_t szWlr  = align256((size_t)NLAYER * 512 * 4);         // x2
    size_t szBc   = align256((size_t)NLAYER * DIM * 4);
    size_t szWf   = align256((size_t)NLAYER * NREL * DIM * DIM * 2);
    size_t szRp   = align256((size_t)NREL * (NN + 1) * 4);
    size_t szNxt  = align256((size_t)NREL * NN * 4);
    size_t szCsr  = align256((size_t)NREL * NEDGE * 4);
    size_t szScn  = align256((size_t)NREL * SNB * 4) * 2;
    size_t need = 4 * szElEr + 2 * szXbf + 2 * szWlr + szBc + szWf + szRp + szNxt + szCsr + szScn;

    if (ws_size < need) {
        k_constf<<<(NN * DIM + 255) / 256, 256, 0, stream>>>((float*)d_out, NN * DIM, 100.0f);
        return;
    }

    char* base = (char*)d_ws;
    size_t off = 0;
    auto alloc = [&](size_t bytes) -> char* { char* p = base + off; off += align256(bytes); return p; };

    float* el   = (float*)alloc((size_t)NREL * NN * 4);
    float* er   = (float*)alloc((size_t)NREL * NN * 4);
    float* el2  = (float*)alloc((size_t)NREL * NN * 4);
    float* er2  = (float*)alloc((size_t)NREL * NN * 4);
    unsigned short* xbf  = (unsigned short*)alloc((size_t)NN * DIM * 2);
    unsigned short* xbf2 = (unsigned short*)alloc((size_t)NN * DIM * 2);
    float* wl    = (float*)alloc((size_t)NLAYER * 512 * 4);
    float* wr    = (float*)alloc((size_t)NLAYER * 512 * 4);
    float* biasc = (float*)alloc((size_t)NLAYER * DIM * 4);
    unsigned short* wfrag = (unsigned short*)alloc((size_t)NLAYER * NREL * DIM * DIM * 2);
    int* rowp = (int*)alloc((size_t)NREL * (NN + 1) * 4);
    int* nxt  = (int*)alloc((size_t)NREL * NN * 4);
    int* csr  = (int*)alloc((size_t)NREL * NEDGE * 4);
    int* bsum = (int*)alloc((size_t)NREL * SNB * 4);
    int* boff = (int*)alloc((size_t)NREL * SNB * 4);

    // ---- CSR build + prep + layer-0 el/er ----
    (void)hipMemsetAsync(nxt, 0, (size_t)NREL * NN * 4, stream);
    k_count<<<dim3((NEDGE + 255) / 256, NREL), 256, 0, stream>>>(edge_dst, nxt);
    k_s1<<<dim3(SNB, NREL), 256, 0, stream>>>(nxt, bsum);
    k_s2<<<1, 256, 0, stream>>>(bsum, boff);
    k_s3<<<dim3(SNB, NREL), 256, 0, stream>>>(nxt, boff, rowp);
    k_copynext<<<dim3((NN + 255) / 256, NREL), 256, 0, stream>>>(rowp, nxt);
    k_fill<<<dim3((NEDGE + 255) / 256, NREL), 256, 0, stream>>>(edge_src, edge_dst, nxt, csr);
    k_prep<<<NLAYER * 512 + 2 + NN * DIM / 1024, 256, 0, stream>>>(
        W_src, W_dst, attn_l, attn_r, ntype_b, gat_bias, h, wfrag, wl, wr, biasc, xbf);
    k_er0<<<(NN + 31) / 32, 256, 0, stream>>>(h, wl, wr, el, er);

    // ---- layers (ping-pong xbf / el / er) ----
    float* dout = (float*)d_out;
    // l = 0: in (xbf, el, er) -> out (xbf2, el2, er2)
    k_fused<<<NN / 16, 256, 0, stream>>>(xbf, el, er, rowp, csr, wfrag, biasc, ln_g, ln_b,
                                         wl, wr, dout, xbf2, el2, er2, 0, 0);
    // l = 1: in (xbf2, el2, er2) -> out (xbf, el, er)
    k_fused<<<NN / 16, 256, 0, stream>>>(xbf2, el2, er2, rowp, csr, wfrag, biasc, ln_g, ln_b,
                                         wl, wr, dout, xbf, el, er, 1, 0);
    // l = 2 (last): in (xbf, el, er) -> d_out
    k_fused<<<NN / 16, 256, 0, stream>>>(xbf, el, er, rowp, csr, wfrag, biasc, ln_g, ln_b,
                                         wl, wr, dout, xbf2, el2, er2, 2, 1);
}